// Round 2
// baseline (94.971 us; speedup 1.0000x reference)
//
#include <hip/hip_runtime.h>
#include <math.h>

// Problem constants (fixed by the reference file)
constexpr int B  = 1024;
constexpr int NL = 64;
constexpr int W  = 2048;
constexpr int INNER = NL - 2;            // layers 1..62 inclusive -> 62 layers
constexpr float EPS_N = 1e-8f;
constexpr float EPS_Y = 1e-9f;

typedef float v2f __attribute__((ext_vector_type(2)));

// FOUR wavelengths per thread, as two independent packed pairs. State packed
// ACROSS wavelengths so every VOP3P operand is a natural VGPR pair:
//   av=(a_w0,a_w1) bv=(b_w0,b_w1) cv=(c_w0,c_w1) dv=(d_w0,d_w1)   (x2 pairs)
// with M = [[a, i*b],[i*c, d]] (closed form under layer products, all real).
// Per-layer constants are stored PRE-DUPLICATED in LDS as pairs
//   (nd,nd,n,n) and (rc,rc)  with rc = 1/(n+eps)
// so phi/ns/sn are single v_pk_mul off the ds_read with no v_mov duplication.
// Update per layer (signs fold into VOP3P neg modifiers):
//   a' = a*c + b*(n*s);  b' = b*c - a*(s/n)
//   c' = c*c - d*(n*s);  d' = d*c + c*(s/n)
// phi tracked in REVOLUTIONS so v_sin_f32/v_cos_f32 are single trans ops.
// Two independent chains per thread hide trans + LDS latency; grid is
// exactly 8 blocks/CU (one residency round).
__global__ __launch_bounds__(256)
void tmm_kernel(const float* __restrict__ n_layers,
                const float* __restrict__ d_layers,
                const float* __restrict__ wavelengths,
                float* __restrict__ out)
{
    __shared__ float4 s_layer[INNER][2];   // [i][0]=(nd,nd,n,n) [i][1]=(rc,rc,0,0)
    __shared__ float  s_edge[2];           // n_in, n_sub

    const int b   = blockIdx.y;
    const int tid = threadIdx.x;
    const int w0  = blockIdx.x * 1024 + tid * 4;

    if (tid < INNER) {
        const float n  = n_layers[b * NL + 1 + tid];
        const float d  = d_layers[b * NL + 1 + tid];
        const float nd = n * d;
        const float rc = 1.0f / (n + EPS_N);
        s_layer[tid][0] = make_float4(nd, nd, n, n);
        s_layer[tid][1] = make_float4(rc, rc, 0.0f, 0.0f);
    }
    if (tid == INNER) {
        s_edge[0] = n_layers[b * NL];                      // n_in
        s_edge[1] = n_layers[b * NL + NL - 1];             // n_sub
    }
    __syncthreads();

    const float4 wl = *(const float4*)&wavelengths[w0];
    const v2f invl0 = { 1.0f / wl.x, 1.0f / wl.y };        // k0 in revolutions
    const v2f invl1 = { 1.0f / wl.z, 1.0f / wl.w };

    v2f av0 = {1.0f, 1.0f}, bv0 = {0.0f, 0.0f}, cv0 = {0.0f, 0.0f}, dv0 = {1.0f, 1.0f};
    v2f av1 = {1.0f, 1.0f}, bv1 = {0.0f, 0.0f}, cv1 = {0.0f, 0.0f}, dv1 = {1.0f, 1.0f};

    #pragma unroll
    for (int i = 0; i < INNER; ++i) {
        const float4 A  = s_layer[i][0];                   // ds_read_b128 (uniform bcast)
        const float2 Rr = *(const float2*)&s_layer[i][1];  // ds_read_b64
        const v2f nd2 = {A.x, A.y};                        // adjacent VGPRs from b128
        const v2f nn2 = {A.z, A.w};
        const v2f rr2 = {Rr.x, Rr.y};

        const v2f ph0 = nd2 * invl0;                       // 2 pk_mul
        const v2f ph1 = nd2 * invl1;

        v2f s0, c0, s1, c1;                                // 8 trans, 2 indep chains
        s0.x = __builtin_amdgcn_sinf(ph0.x);
        s0.y = __builtin_amdgcn_sinf(ph0.y);
        s1.x = __builtin_amdgcn_sinf(ph1.x);
        s1.y = __builtin_amdgcn_sinf(ph1.y);
        c0.x = __builtin_amdgcn_cosf(ph0.x);
        c0.y = __builtin_amdgcn_cosf(ph0.y);
        c1.x = __builtin_amdgcn_cosf(ph1.x);
        c1.y = __builtin_amdgcn_cosf(ph1.y);

        const v2f ns0 = nn2 * s0;                          // 4 pk_mul
        const v2f sn0 = rr2 * s0;
        const v2f ns1 = nn2 * s1;
        const v2f sn1 = rr2 * s1;

        const v2f an0 = __builtin_elementwise_fma(bv0,  ns0, av0 * c0);  // 16 pk
        const v2f bn0 = __builtin_elementwise_fma(-av0, sn0, bv0 * c0);
        const v2f cn0 = __builtin_elementwise_fma(-dv0, ns0, cv0 * c0);
        const v2f dn0 = __builtin_elementwise_fma(cv0,  sn0, dv0 * c0);
        const v2f an1 = __builtin_elementwise_fma(bv1,  ns1, av1 * c1);
        const v2f bn1 = __builtin_elementwise_fma(-av1, sn1, bv1 * c1);
        const v2f cn1 = __builtin_elementwise_fma(-dv1, ns1, cv1 * c1);
        const v2f dn1 = __builtin_elementwise_fma(cv1,  sn1, dv1 * c1);
        av0 = an0; bv0 = bn0; cv0 = cn0; dv0 = dn0;
        av1 = an1; bv1 = bn1; cv1 = cn1; dv1 = dn1;
    }

    const float n_in  = s_edge[0];
    const float n_sub = s_edge[1];

    // E = a + eps_Y + i*(b*n_sub);  H = d*n_sub + i*c;  R = |nE-H|^2 / |nE+H|^2
    float4 Rout;
    {
        const float Er = av0.x + EPS_Y, Ei = bv0.x * n_sub;
        const float Hr = dv0.x * n_sub, Hi = cv0.x;
        const float Nr = fmaf(n_in, Er, -Hr), Ni = fmaf(n_in, Ei, -Hi);
        const float Dr = fmaf(n_in, Er,  Hr), Di = fmaf(n_in, Ei,  Hi);
        Rout.x = (Nr * Nr + Ni * Ni) / (Dr * Dr + Di * Di);
    }
    {
        const float Er = av0.y + EPS_Y, Ei = bv0.y * n_sub;
        const float Hr = dv0.y * n_sub, Hi = cv0.y;
        const float Nr = fmaf(n_in, Er, -Hr), Ni = fmaf(n_in, Ei, -Hi);
        const float Dr = fmaf(n_in, Er,  Hr), Di = fmaf(n_in, Ei,  Hi);
        Rout.y = (Nr * Nr + Ni * Ni) / (Dr * Dr + Di * Di);
    }
    {
        const float Er = av1.x + EPS_Y, Ei = bv1.x * n_sub;
        const float Hr = dv1.x * n_sub, Hi = cv1.x;
        const float Nr = fmaf(n_in, Er, -Hr), Ni = fmaf(n_in, Ei, -Hi);
        const float Dr = fmaf(n_in, Er,  Hr), Di = fmaf(n_in, Ei,  Hi);
        Rout.z = (Nr * Nr + Ni * Ni) / (Dr * Dr + Di * Di);
    }
    {
        const float Er = av1.y + EPS_Y, Ei = bv1.y * n_sub;
        const float Hr = dv1.y * n_sub, Hi = cv1.y;
        const float Nr = fmaf(n_in, Er, -Hr), Ni = fmaf(n_in, Ei, -Hi);
        const float Dr = fmaf(n_in, Er,  Hr), Di = fmaf(n_in, Ei,  Hi);
        Rout.w = (Nr * Nr + Ni * Ni) / (Dr * Dr + Di * Di);
    }
    *(float4*)&out[b * W + w0] = Rout;     // coalesced 16B/lane store

}

extern "C" void kernel_launch(void* const* d_in, const int* in_sizes, int n_in,
                              void* d_out, int out_size, void* d_ws, size_t ws_size,
                              hipStream_t stream)
{
    const float* n_layers    = (const float*)d_in[0];
    const float* d_layers    = (const float*)d_in[1];
    const float* wavelengths = (const float*)d_in[2];
    float* out = (float*)d_out;

    dim3 grid(W / 1024, B);                // 4 wavelengths per thread, 8 blocks/CU
    dim3 block(256);
    tmm_kernel<<<grid, block, 0, stream>>>(n_layers, d_layers, wavelengths, out);
}